// Round 6
// baseline (172.647 us; speedup 1.0000x reference)
//
#include <hip/hip_runtime.h>

#define N_NODES_C 50000
#define F_IN_C 64
#define HID_C 128
#define N_GRAPHS_C 500
#define N_CLS_C 10
#define MLP_HID_C 50
#define SCAN_TILE 1024
#define N_SCAN_BLK ((N_NODES_C + SCAN_TILE - 1) / SCAN_TILE)   // 49
#define N_TILES (N_NODES_C / 16)                               // 3125

using short8 = __attribute__((ext_vector_type(8))) short;
using f32x4  = __attribute__((ext_vector_type(4))) float;

__device__ __forceinline__ int bl_i(int v, int l) {
    return __builtin_amdgcn_readlane(v, l);
}
__device__ __forceinline__ float uf(unsigned u) { return __uint_as_float(u); }

// round-to-nearest-even bf16 pack of two floats -> (lo=a, hi=b)
__device__ __forceinline__ unsigned pk_bf16(float a, float b) {
    unsigned ua = __float_as_uint(a), ub = __float_as_uint(b);
    ua += 0x7FFFu + ((ua >> 16) & 1u);
    ub += 0x7FFFu + ((ub >> 16) & 1u);
    return (ua >> 16) | (ub & 0xFFFF0000u);
}

union U8 { unsigned u[4]; short8 s; };

// ---------------------------------------------------------------------------
// Stage 1: degree histogram + graph bounds from sorted batch.
// ---------------------------------------------------------------------------
__global__ __launch_bounds__(256) void hist_kernel(
    const int* __restrict__ dst,
    const int* __restrict__ batch,
    int* __restrict__ deg_i,
    int* __restrict__ start,
    int n_edges)
{
    int tid = blockIdx.x * 256 + threadIdx.x;
    int stride = gridDim.x * 256;
    for (int e = tid; e < n_edges; e += stride)
        atomicAdd(&deg_i[dst[e]], 1);
    for (int i = tid; i < N_NODES_C; i += stride) {
        int b = batch[i];
        if (i == 0) { for (int g = 0; g <= b; ++g) start[g] = 0; }
        else { int p = batch[i - 1]; for (int g = p + 1; g <= b; ++g) start[g] = i; }
        if (i == N_NODES_C - 1) { for (int g = b + 1; g <= N_GRAPHS_C; ++g) start[g] = N_NODES_C; }
    }
}

// Stage 2a: per-1024-tile sums
__global__ __launch_bounds__(256) void scan1_kernel(
    const int* __restrict__ deg_i, int* __restrict__ bsums, int n)
{
    __shared__ int s[256];
    int base = blockIdx.x * SCAN_TILE;
    int t = threadIdx.x;
    int sum = 0;
    #pragma unroll
    for (int j = 0; j < 4; ++j) {
        int i = base + t * 4 + j;
        sum += (i < n) ? deg_i[i] : 0;
    }
    s[t] = sum;
    __syncthreads();
    for (int off = 128; off > 0; off >>= 1) {
        if (t < off) s[t] += s[t + off];
        __syncthreads();
    }
    if (t == 0) bsums[blockIdx.x] = s[0];
}

// Stage 2b (fused): tile-prefix via wave-reduce of bsums + intra-tile scan.
// Writes off[] and cursor[] (scatter's atomic base).
__global__ __launch_bounds__(256) void scan3_kernel(
    const int* __restrict__ deg_i, const int* __restrict__ bsums,
    int* __restrict__ off, int* __restrict__ cursor, int n)
{
    __shared__ int s[256];
    __shared__ int sbp;
    int b = blockIdx.x;
    int t = threadIdx.x;
    if (t < 64) {
        int v = (t < b) ? bsums[t] : 0;      // b <= 48 < 64
        #pragma unroll
        for (int m = 1; m < 64; m <<= 1) v += __shfl_xor(v, m, 64);
        if (t == 0) sbp = v;
    }
    int base = b * SCAN_TILE;
    int v4[4];
    int sum = 0;
    #pragma unroll
    for (int j = 0; j < 4; ++j) {
        int i = base + t * 4 + j;
        v4[j] = (i < n) ? deg_i[i] : 0;
        sum += v4[j];
    }
    s[t] = sum;
    __syncthreads();
    for (int o = 1; o < 256; o <<= 1) {
        int tmp = (t >= o) ? s[t - o] : 0;
        __syncthreads();
        s[t] += tmp;
        __syncthreads();
    }
    int run = s[t] - sum + sbp;
    #pragma unroll
    for (int j = 0; j < 4; ++j) {
        int i = base + t * 4 + j;
        if (i < n) { off[i] = run; cursor[i] = run; }
        run += v4[j];
    }
    if (b == N_SCAN_BLK - 1 && t == 255) off[n] = sbp + s[255];
}

// Stage 3: scatter via atomic cursor
__global__ __launch_bounds__(256) void scatter_kernel(
    const int* __restrict__ src, const int* __restrict__ dst,
    int* __restrict__ cursor, int* __restrict__ adj, int n_edges)
{
    int e = blockIdx.x * 256 + threadIdx.x;
    if (e >= n_edges) return;
    int p = atomicAdd(&cursor[dst[e]], 1);
    adj[p] = src[e];
}

// ---------------------------------------------------------------------------
// MFMA GEMM: Y = X @ [Ws | Wn]  (M=50000, K=64, N=256).
// Cols 0..127  (Ws) -> emb_out f32 (+bias).
// Cols 128..255 (Wn) -> yn bf16-packed: yn[row][q] = pack(col q, col q+64).
// One 16-row tile per wave; 782 blocks x 4 waves.
// ---------------------------------------------------------------------------
__global__ __launch_bounds__(256) void gemm_kernel(
    const float* __restrict__ x,
    const float* __restrict__ Wn,
    const float* __restrict__ Ws,
    const float* __restrict__ bias,
    float* __restrict__ emb_out,
    unsigned* __restrict__ yn)
{
    __shared__ unsigned sWk[32 * 256];   // sWk[m][n] = pack(W256[2m][n], W256[2m+1][n])
    __shared__ float sb[128];
    int t = threadIdx.x;
    for (int e = t; e < 32 * 256; e += 256) {
        int m = e >> 8, n = e & 255;
        float w0, w1;
        if (n < 128) { w0 = Ws[(2 * m) * 128 + n];       w1 = Ws[(2 * m + 1) * 128 + n]; }
        else         { w0 = Wn[(2 * m) * 128 + n - 128]; w1 = Wn[(2 * m + 1) * 128 + n - 128]; }
        sWk[e] = pk_bf16(w0, w1);
    }
    if (t < 128) sb[t] = bias[t];
    __syncthreads();

    int wave = t >> 6, lane = t & 63;
    int lr = lane & 15, lg = lane >> 4;
    int tile = blockIdx.x * 4 + wave;
    if (tile >= N_TILES) return;

    // A frags: row = tile*16 + lr, k = 8*lg + j  (A0: k 0..31, A1: k 32..63)
    const float4* xr = (const float4*)(x + ((size_t)tile * 16 + lr) * 64);
    float4 p0 = xr[lg * 2], p1 = xr[lg * 2 + 1];
    float4 p2 = xr[8 + lg * 2], p3 = xr[8 + lg * 2 + 1];
    U8 A0, A1;
    A0.u[0] = pk_bf16(p0.x, p0.y); A0.u[1] = pk_bf16(p0.z, p0.w);
    A0.u[2] = pk_bf16(p1.x, p1.y); A0.u[3] = pk_bf16(p1.z, p1.w);
    A1.u[0] = pk_bf16(p2.x, p2.y); A1.u[1] = pk_bf16(p2.z, p2.w);
    A1.u[2] = pk_bf16(p3.x, p3.y); A1.u[3] = pk_bf16(p3.z, p3.w);

    // f32 half (Ws + bias) -> emb_out
    #pragma unroll
    for (int c = 0; c < 8; ++c) {
        U8 B0, B1;
        #pragma unroll
        for (int jj = 0; jj < 4; ++jj) {
            B0.u[jj] = sWk[(4 * lg + jj) * 256 + c * 16 + lr];
            B1.u[jj] = sWk[(16 + 4 * lg + jj) * 256 + c * 16 + lr];
        }
        float bv = sb[c * 16 + lr];
        f32x4 acc = {bv, bv, bv, bv};
        acc = __builtin_amdgcn_mfma_f32_16x16x32_bf16(A0.s, B0.s, acc, 0, 0, 0);
        acc = __builtin_amdgcn_mfma_f32_16x16x32_bf16(A1.s, B1.s, acc, 0, 0, 0);
        #pragma unroll
        for (int r = 0; r < 4; ++r)
            emb_out[((size_t)tile * 16 + lg * 4 + r) * 128 + c * 16 + lr] = acc[r];
    }
    // bf16 half (Wn) -> yn, pack col pairs (q, q+64)
    #pragma unroll
    for (int cc = 0; cc < 4; ++cc) {
        U8 B0a, B1a, B0b, B1b;
        #pragma unroll
        for (int jj = 0; jj < 4; ++jj) {
            B0a.u[jj] = sWk[(4 * lg + jj) * 256 + (8 + cc) * 16 + lr];
            B1a.u[jj] = sWk[(16 + 4 * lg + jj) * 256 + (8 + cc) * 16 + lr];
            B0b.u[jj] = sWk[(4 * lg + jj) * 256 + (12 + cc) * 16 + lr];
            B1b.u[jj] = sWk[(16 + 4 * lg + jj) * 256 + (12 + cc) * 16 + lr];
        }
        f32x4 aN = {0.f, 0.f, 0.f, 0.f}, aM = {0.f, 0.f, 0.f, 0.f};
        aN = __builtin_amdgcn_mfma_f32_16x16x32_bf16(A0.s, B0a.s, aN, 0, 0, 0);
        aN = __builtin_amdgcn_mfma_f32_16x16x32_bf16(A1.s, B1a.s, aN, 0, 0, 0);
        aM = __builtin_amdgcn_mfma_f32_16x16x32_bf16(A0.s, B0b.s, aM, 0, 0, 0);
        aM = __builtin_amdgcn_mfma_f32_16x16x32_bf16(A1.s, B1b.s, aM, 0, 0, 0);
        #pragma unroll
        for (int r = 0; r < 4; ++r)
            yn[((size_t)tile * 16 + lg * 4 + r) * 64 + cc * 16 + lr] =
                pk_bf16(aN[r], aM[r]);
    }
}

// ---------------------------------------------------------------------------
// Gather-add: emb_row += mean of neighbors' Yn rows. ONE WAVE PER NODE,
// unroll-8 independent row loads for deep memory pipelining.
// lane = u32 index (cols l, l+64).
// ---------------------------------------------------------------------------
__global__ __launch_bounds__(256) void gather_add_kernel(
    const unsigned* __restrict__ yn,
    const int* __restrict__ adj,
    const int* __restrict__ off,
    float* __restrict__ emb)
{
    int t = threadIdx.x;
    int wave = t >> 6, lane = t & 63;
    int node = blockIdx.x * 4 + wave;     // grid 12500 x 4 waves = 50000 exact
    int o = off[node];
    int d = off[node + 1] - o;
    float sx = 0.f, sy = 0.f;
    for (int j0 = 0; j0 < d; j0 += 64) {
        int c = d - j0; if (c > 64) c = 64;
        int nid = (lane < c) ? adj[o + j0 + lane] : 0;
        int j = 0;
        for (; j + 8 <= c; j += 8) {
            unsigned u0 = yn[(size_t)bl_i(nid, j + 0) * 64 + lane];
            unsigned u1 = yn[(size_t)bl_i(nid, j + 1) * 64 + lane];
            unsigned u2 = yn[(size_t)bl_i(nid, j + 2) * 64 + lane];
            unsigned u3 = yn[(size_t)bl_i(nid, j + 3) * 64 + lane];
            unsigned u4 = yn[(size_t)bl_i(nid, j + 4) * 64 + lane];
            unsigned u5 = yn[(size_t)bl_i(nid, j + 5) * 64 + lane];
            unsigned u6 = yn[(size_t)bl_i(nid, j + 6) * 64 + lane];
            unsigned u7 = yn[(size_t)bl_i(nid, j + 7) * 64 + lane];
            sx += uf(u0 << 16); sy += uf(u0 & 0xFFFF0000u);
            sx += uf(u1 << 16); sy += uf(u1 & 0xFFFF0000u);
            sx += uf(u2 << 16); sy += uf(u2 & 0xFFFF0000u);
            sx += uf(u3 << 16); sy += uf(u3 & 0xFFFF0000u);
            sx += uf(u4 << 16); sy += uf(u4 & 0xFFFF0000u);
            sx += uf(u5 << 16); sy += uf(u5 & 0xFFFF0000u);
            sx += uf(u6 << 16); sy += uf(u6 & 0xFFFF0000u);
            sx += uf(u7 << 16); sy += uf(u7 & 0xFFFF0000u);
        }
        for (; j < c; ++j) {
            unsigned u = yn[(size_t)bl_i(nid, j) * 64 + lane];
            sx += uf(u << 16); sy += uf(u & 0xFFFF0000u);
        }
    }
    float inv = 1.0f / fmaxf((float)d, 1.0f);
    size_t b = (size_t)node * 128;
    emb[b + lane]      += sx * inv;
    emb[b + 64 + lane] += sy * inv;
}

// ---------------------------------------------------------------------------
// Fused segment mean-pool of relu(emb) + MLP head + log_softmax.
// ---------------------------------------------------------------------------
__global__ __launch_bounds__(256) void poolhead_kernel(
    const float* __restrict__ emb, const int* __restrict__ start,
    const float* __restrict__ W1, const float* __restrict__ b1,
    const float* __restrict__ W2, const float* __restrict__ b2,
    float* __restrict__ logits_out)
{
    int g = blockIdx.x;
    int t = threadIdx.x;
    __shared__ float sp[HID_C];
    __shared__ float shid[MLP_HID_C];
    __shared__ float sl[N_CLS_C];
    __shared__ float4 red[256];

    int s0 = start[g], e0 = start[g + 1];
    int q = t & 31, r0 = t >> 5;
    const float4* e4 = (const float4*)emb;
    float4 acc = make_float4(0.f, 0.f, 0.f, 0.f);
    for (int r = s0 + r0; r < e0; r += 8) {
        float4 v = e4[(size_t)r * 32 + q];
        acc.x += fmaxf(v.x, 0.f); acc.y += fmaxf(v.y, 0.f);
        acc.z += fmaxf(v.z, 0.f); acc.w += fmaxf(v.w, 0.f);
    }
    red[t] = acc;
    __syncthreads();
    if (t < 32) {
        float4 a = red[t];
        #pragma unroll
        for (int r = 1; r < 8; ++r) {
            float4 b = red[t + 32 * r];
            a.x += b.x; a.y += b.y; a.z += b.z; a.w += b.w;
        }
        float inv = 1.0f / fmaxf((float)(e0 - s0), 1.0f);
        ((float4*)sp)[t] = make_float4(a.x * inv, a.y * inv, a.z * inv, a.w * inv);
    }
    __syncthreads();

    if (t < MLP_HID_C) {
        float a = b1[t];
        #pragma unroll 8
        for (int k = 0; k < HID_C; ++k) a += sp[k] * W1[k * MLP_HID_C + t];
        shid[t] = fmaxf(a, 0.0f);
    }
    __syncthreads();

    if (t < N_CLS_C) {
        float a = b2[t];
        #pragma unroll
        for (int k = 0; k < MLP_HID_C; ++k) a += shid[k] * W2[k * N_CLS_C + t];
        sl[t] = a;
    }
    __syncthreads();

    if (t < N_CLS_C) {
        float m = sl[0];
        #pragma unroll
        for (int i = 1; i < N_CLS_C; ++i) m = fmaxf(m, sl[i]);
        float sum = 0.0f;
        #pragma unroll
        for (int i = 0; i < N_CLS_C; ++i) sum += expf(sl[i] - m);
        logits_out[(size_t)g * N_CLS_C + t] = sl[t] - m - logf(sum);
    }
}

extern "C" void kernel_launch(void* const* d_in, const int* in_sizes, int n_in,
                              void* d_out, int out_size, void* d_ws, size_t ws_size,
                              hipStream_t stream) {
    const float* x      = (const float*)d_in[0];
    const int*   ei     = (const int*)d_in[1];
    const int*   batch  = (const int*)d_in[2];
    const float* Wn     = (const float*)d_in[3];
    const float* Ws     = (const float*)d_in[4];
    const float* bias   = (const float*)d_in[5];
    const float* W1     = (const float*)d_in[6];
    const float* b1     = (const float*)d_in[7];
    const float* W2     = (const float*)d_in[8];
    const float* b2     = (const float*)d_in[9];

    float* out = (float*)d_out;
    int n_edges = in_sizes[1] / 2;
    const int* src = ei;
    const int* dst = ei + n_edges;

    // ws (ints): deg_i[N] | off[N+1] | cursor[N] | bsums[64] | start[G+1] |
    //            adj[E] | yn[N*64 u32]
    int* deg_i   = (int*)d_ws;
    int* off     = deg_i + N_NODES_C;
    int* cursor  = off + (N_NODES_C + 1);
    int* bsums   = cursor + N_NODES_C;
    int* start   = bsums + 64;
    int* adj     = start + (N_GRAPHS_C + 1);
    unsigned* yn = (unsigned*)(adj + n_edges);

    hipMemsetAsync(deg_i, 0, (size_t)N_NODES_C * sizeof(int), stream);

    int eblk = (n_edges + 255) / 256;
    hist_kernel<<<1024, 256, 0, stream>>>(dst, batch, deg_i, start, n_edges);
    scan1_kernel<<<N_SCAN_BLK, 256, 0, stream>>>(deg_i, bsums, N_NODES_C);
    scan3_kernel<<<N_SCAN_BLK, 256, 0, stream>>>(deg_i, bsums, off, cursor, N_NODES_C);
    scatter_kernel<<<eblk, 256, 0, stream>>>(src, dst, cursor, adj, n_edges);

    gemm_kernel<<<782, 256, 0, stream>>>(x, Wn, Ws, bias, out, yn);

    gather_add_kernel<<<12500, 256, 0, stream>>>(yn, adj, off, out);

    poolhead_kernel<<<N_GRAPHS_C, 256, 0, stream>>>(out, start, W1, b1, W2, b2,
                                                    out + (size_t)N_NODES_C * HID_C);
}

// Round 7
// 156.760 us; speedup vs baseline: 1.1013x; 1.1013x over previous
//
#include <hip/hip_runtime.h>

#define N_NODES_C 50000
#define F_IN_C 64
#define HID_C 128
#define N_GRAPHS_C 500
#define N_CLS_C 10
#define MLP_HID_C 50
#define SCAN_TILE 1024
#define N_SCAN_BLK ((N_NODES_C + SCAN_TILE - 1) / SCAN_TILE)   // 49
#define N_TILES (N_NODES_C / 16)                               // 3125
#define N_RANGES 8
#define RANGE_SZ ((N_NODES_C + N_RANGES - 1) / N_RANGES)       // 6250

using short8 = __attribute__((ext_vector_type(8))) short;
using f32x4  = __attribute__((ext_vector_type(4))) float;

__device__ __forceinline__ int bl_i(int v, int l) {
    return __builtin_amdgcn_readlane(v, l);
}
__device__ __forceinline__ float uf(unsigned u) { return __uint_as_float(u); }

// round-to-nearest-even bf16 pack of two floats -> (lo=a, hi=b)
__device__ __forceinline__ unsigned pk_bf16(float a, float b) {
    unsigned ua = __float_as_uint(a), ub = __float_as_uint(b);
    ua += 0x7FFFu + ((ua >> 16) & 1u);
    ub += 0x7FFFu + ((ub >> 16) & 1u);
    return (ua >> 16) | (ub & 0xFFFF0000u);
}

union U8 { unsigned u[4]; short8 s; };

// ---------------------------------------------------------------------------
// Stage 1: degree histogram + graph bounds from sorted batch.
// ---------------------------------------------------------------------------
__global__ __launch_bounds__(256) void hist_kernel(
    const int* __restrict__ dst,
    const int* __restrict__ batch,
    int* __restrict__ deg_i,
    int* __restrict__ start,
    int n_edges)
{
    int tid = blockIdx.x * 256 + threadIdx.x;
    int stride = gridDim.x * 256;
    for (int e = tid; e < n_edges; e += stride)
        atomicAdd(&deg_i[dst[e]], 1);
    for (int i = tid; i < N_NODES_C; i += stride) {
        int b = batch[i];
        if (i == 0) { for (int g = 0; g <= b; ++g) start[g] = 0; }
        else { int p = batch[i - 1]; for (int g = p + 1; g <= b; ++g) start[g] = i; }
        if (i == N_NODES_C - 1) { for (int g = b + 1; g <= N_GRAPHS_C; ++g) start[g] = N_NODES_C; }
    }
}

// Stage 2a: per-1024-tile sums
__global__ __launch_bounds__(256) void scan1_kernel(
    const int* __restrict__ deg_i, int* __restrict__ bsums, int n)
{
    __shared__ int s[256];
    int base = blockIdx.x * SCAN_TILE;
    int t = threadIdx.x;
    int sum = 0;
    #pragma unroll
    for (int j = 0; j < 4; ++j) {
        int i = base + t * 4 + j;
        sum += (i < n) ? deg_i[i] : 0;
    }
    s[t] = sum;
    __syncthreads();
    for (int off = 128; off > 0; off >>= 1) {
        if (t < off) s[t] += s[t + off];
        __syncthreads();
    }
    if (t == 0) bsums[blockIdx.x] = s[0];
}

// Stage 2b (fused): tile-prefix via wave-reduce of bsums + intra-tile scan.
// Writes off[] and cursor[] (scatter's atomic base).
__global__ __launch_bounds__(256) void scan3_kernel(
    const int* __restrict__ deg_i, const int* __restrict__ bsums,
    int* __restrict__ off, int* __restrict__ cursor, int n)
{
    __shared__ int s[256];
    __shared__ int sbp;
    int b = blockIdx.x;
    int t = threadIdx.x;
    if (t < 64) {
        int v = (t < b) ? bsums[t] : 0;      // b <= 48 < 64
        #pragma unroll
        for (int m = 1; m < 64; m <<= 1) v += __shfl_xor(v, m, 64);
        if (t == 0) sbp = v;
    }
    int base = b * SCAN_TILE;
    int v4[4];
    int sum = 0;
    #pragma unroll
    for (int j = 0; j < 4; ++j) {
        int i = base + t * 4 + j;
        v4[j] = (i < n) ? deg_i[i] : 0;
        sum += v4[j];
    }
    s[t] = sum;
    __syncthreads();
    for (int o = 1; o < 256; o <<= 1) {
        int tmp = (t >= o) ? s[t - o] : 0;
        __syncthreads();
        s[t] += tmp;
        __syncthreads();
    }
    int run = s[t] - sum + sbp;
    #pragma unroll
    for (int j = 0; j < 4; ++j) {
        int i = base + t * 4 + j;
        if (i < n) { off[i] = run; cursor[i] = run; }
        run += v4[j];
    }
    if (b == N_SCAN_BLK - 1 && t == 255) off[n] = sbp + s[255];
}

// ---------------------------------------------------------------------------
// Stage 3: XCD-range-partitioned scatter. Group g = blockIdx & 7 handles only
// dst in [g*RANGE_SZ, (g+1)*RANGE_SZ): with the blockIdx%8 -> XCD round-robin
// mapping, each range's adj/cursor lines are written by one XCD's L2 only,
// killing the 16x cross-XCD write amplification. Reads are re-scanned 8x
// (cheap, streaming).
// ---------------------------------------------------------------------------
__global__ __launch_bounds__(256) void scatter_kernel(
    const int* __restrict__ src, const int* __restrict__ dst,
    int* __restrict__ cursor, int* __restrict__ adj, int n_edges)
{
    int g = blockIdx.x & 7;
    int lo = g * RANGE_SZ;
    int e0 = (blockIdx.x >> 3) * 256 + threadIdx.x;
    for (int e = e0; e < n_edges; e += 65536) {   // (2048/8) blocks * 256 thr
        int d = dst[e];
        if ((unsigned)(d - lo) < (unsigned)RANGE_SZ) {
            int p = atomicAdd(&cursor[d], 1);
            adj[p] = src[e];
        }
    }
}

// ---------------------------------------------------------------------------
// MFMA GEMM: Y = X @ [Ws | Wn]  (M=50000, K=64, N=256).
// Cols 0..127  (Ws) -> emb_out f32 (+bias).
// Cols 128..255 (Wn) -> yn bf16-packed: yn[row][q] = pack(col q, col q+64).
// One 16-row tile per wave; 782 blocks x 4 waves.
// ---------------------------------------------------------------------------
__global__ __launch_bounds__(256) void gemm_kernel(
    const float* __restrict__ x,
    const float* __restrict__ Wn,
    const float* __restrict__ Ws,
    const float* __restrict__ bias,
    float* __restrict__ emb_out,
    unsigned* __restrict__ yn)
{
    __shared__ unsigned sWk[32 * 256];   // sWk[m][n] = pack(W256[2m][n], W256[2m+1][n])
    __shared__ float sb[128];
    int t = threadIdx.x;
    for (int e = t; e < 32 * 256; e += 256) {
        int m = e >> 8, n = e & 255;
        float w0, w1;
        if (n < 128) { w0 = Ws[(2 * m) * 128 + n];       w1 = Ws[(2 * m + 1) * 128 + n]; }
        else         { w0 = Wn[(2 * m) * 128 + n - 128]; w1 = Wn[(2 * m + 1) * 128 + n - 128]; }
        sWk[e] = pk_bf16(w0, w1);
    }
    if (t < 128) sb[t] = bias[t];
    __syncthreads();

    int wave = t >> 6, lane = t & 63;
    int lr = lane & 15, lg = lane >> 4;
    int tile = blockIdx.x * 4 + wave;
    if (tile >= N_TILES) return;

    // A frags: row = tile*16 + lr, k = 8*lg + j  (A0: k 0..31, A1: k 32..63)
    const float4* xr = (const float4*)(x + ((size_t)tile * 16 + lr) * 64);
    float4 p0 = xr[lg * 2], p1 = xr[lg * 2 + 1];
    float4 p2 = xr[8 + lg * 2], p3 = xr[8 + lg * 2 + 1];
    U8 A0, A1;
    A0.u[0] = pk_bf16(p0.x, p0.y); A0.u[1] = pk_bf16(p0.z, p0.w);
    A0.u[2] = pk_bf16(p1.x, p1.y); A0.u[3] = pk_bf16(p1.z, p1.w);
    A1.u[0] = pk_bf16(p2.x, p2.y); A1.u[1] = pk_bf16(p2.z, p2.w);
    A1.u[2] = pk_bf16(p3.x, p3.y); A1.u[3] = pk_bf16(p3.z, p3.w);

    // f32 half (Ws + bias) -> emb_out
    #pragma unroll
    for (int c = 0; c < 8; ++c) {
        U8 B0, B1;
        #pragma unroll
        for (int jj = 0; jj < 4; ++jj) {
            B0.u[jj] = sWk[(4 * lg + jj) * 256 + c * 16 + lr];
            B1.u[jj] = sWk[(16 + 4 * lg + jj) * 256 + c * 16 + lr];
        }
        float bv = sb[c * 16 + lr];
        f32x4 acc = {bv, bv, bv, bv};
        acc = __builtin_amdgcn_mfma_f32_16x16x32_bf16(A0.s, B0.s, acc, 0, 0, 0);
        acc = __builtin_amdgcn_mfma_f32_16x16x32_bf16(A1.s, B1.s, acc, 0, 0, 0);
        #pragma unroll
        for (int r = 0; r < 4; ++r)
            emb_out[((size_t)tile * 16 + lg * 4 + r) * 128 + c * 16 + lr] = acc[r];
    }
    // bf16 half (Wn) -> yn, pack col pairs (q, q+64)
    #pragma unroll
    for (int cc = 0; cc < 4; ++cc) {
        U8 B0a, B1a, B0b, B1b;
        #pragma unroll
        for (int jj = 0; jj < 4; ++jj) {
            B0a.u[jj] = sWk[(4 * lg + jj) * 256 + (8 + cc) * 16 + lr];
            B1a.u[jj] = sWk[(16 + 4 * lg + jj) * 256 + (8 + cc) * 16 + lr];
            B0b.u[jj] = sWk[(4 * lg + jj) * 256 + (12 + cc) * 16 + lr];
            B1b.u[jj] = sWk[(16 + 4 * lg + jj) * 256 + (12 + cc) * 16 + lr];
        }
        f32x4 aN = {0.f, 0.f, 0.f, 0.f}, aM = {0.f, 0.f, 0.f, 0.f};
        aN = __builtin_amdgcn_mfma_f32_16x16x32_bf16(A0.s, B0a.s, aN, 0, 0, 0);
        aN = __builtin_amdgcn_mfma_f32_16x16x32_bf16(A1.s, B1a.s, aN, 0, 0, 0);
        aM = __builtin_amdgcn_mfma_f32_16x16x32_bf16(A0.s, B0b.s, aM, 0, 0, 0);
        aM = __builtin_amdgcn_mfma_f32_16x16x32_bf16(A1.s, B1b.s, aM, 0, 0, 0);
        #pragma unroll
        for (int r = 0; r < 4; ++r)
            yn[((size_t)tile * 16 + lg * 4 + r) * 64 + cc * 16 + lr] =
                pk_bf16(aN[r], aM[r]);
    }
}

// ---------------------------------------------------------------------------
// Gather-add: emb_row += mean of neighbors' Yn rows. One wave per node,
// unroll-8 independent row loads. lane = u32 index (cols l, l+64).
// ---------------------------------------------------------------------------
__global__ __launch_bounds__(256) void gather_add_kernel(
    const unsigned* __restrict__ yn,
    const int* __restrict__ adj,
    const int* __restrict__ off,
    float* __restrict__ emb)
{
    int t = threadIdx.x;
    int wave = t >> 6, lane = t & 63;
    int node = blockIdx.x * 4 + wave;     // grid 12500 x 4 waves = 50000 exact
    int o = off[node];
    int d = off[node + 1] - o;
    float sx = 0.f, sy = 0.f;
    for (int j0 = 0; j0 < d; j0 += 64) {
        int c = d - j0; if (c > 64) c = 64;
        int nid = (lane < c) ? adj[o + j0 + lane] : 0;
        int j = 0;
        for (; j + 8 <= c; j += 8) {
            unsigned u0 = yn[(size_t)bl_i(nid, j + 0) * 64 + lane];
            unsigned u1 = yn[(size_t)bl_i(nid, j + 1) * 64 + lane];
            unsigned u2 = yn[(size_t)bl_i(nid, j + 2) * 64 + lane];
            unsigned u3 = yn[(size_t)bl_i(nid, j + 3) * 64 + lane];
            unsigned u4 = yn[(size_t)bl_i(nid, j + 4) * 64 + lane];
            unsigned u5 = yn[(size_t)bl_i(nid, j + 5) * 64 + lane];
            unsigned u6 = yn[(size_t)bl_i(nid, j + 6) * 64 + lane];
            unsigned u7 = yn[(size_t)bl_i(nid, j + 7) * 64 + lane];
            sx += uf(u0 << 16); sy += uf(u0 & 0xFFFF0000u);
            sx += uf(u1 << 16); sy += uf(u1 & 0xFFFF0000u);
            sx += uf(u2 << 16); sy += uf(u2 & 0xFFFF0000u);
            sx += uf(u3 << 16); sy += uf(u3 & 0xFFFF0000u);
            sx += uf(u4 << 16); sy += uf(u4 & 0xFFFF0000u);
            sx += uf(u5 << 16); sy += uf(u5 & 0xFFFF0000u);
            sx += uf(u6 << 16); sy += uf(u6 & 0xFFFF0000u);
            sx += uf(u7 << 16); sy += uf(u7 & 0xFFFF0000u);
        }
        for (; j < c; ++j) {
            unsigned u = yn[(size_t)bl_i(nid, j) * 64 + lane];
            sx += uf(u << 16); sy += uf(u & 0xFFFF0000u);
        }
    }
    float inv = 1.0f / fmaxf((float)d, 1.0f);
    size_t b = (size_t)node * 128;
    emb[b + lane]      += sx * inv;
    emb[b + 64 + lane] += sy * inv;
}

// ---------------------------------------------------------------------------
// Fused segment mean-pool of relu(emb) + MLP head + log_softmax.
// ---------------------------------------------------------------------------
__global__ __launch_bounds__(256) void poolhead_kernel(
    const float* __restrict__ emb, const int* __restrict__ start,
    const float* __restrict__ W1, const float* __restrict__ b1,
    const float* __restrict__ W2, const float* __restrict__ b2,
    float* __restrict__ logits_out)
{
    int g = blockIdx.x;
    int t = threadIdx.x;
    __shared__ float sp[HID_C];
    __shared__ float shid[MLP_HID_C];
    __shared__ float sl[N_CLS_C];
    __shared__ float4 red[256];

    int s0 = start[g], e0 = start[g + 1];
    int q = t & 31, r0 = t >> 5;
    const float4* e4 = (const float4*)emb;
    float4 acc = make_float4(0.f, 0.f, 0.f, 0.f);
    for (int r = s0 + r0; r < e0; r += 8) {
        float4 v = e4[(size_t)r * 32 + q];
        acc.x += fmaxf(v.x, 0.f); acc.y += fmaxf(v.y, 0.f);
        acc.z += fmaxf(v.z, 0.f); acc.w += fmaxf(v.w, 0.f);
    }
    red[t] = acc;
    __syncthreads();
    if (t < 32) {
        float4 a = red[t];
        #pragma unroll
        for (int r = 1; r < 8; ++r) {
            float4 b = red[t + 32 * r];
            a.x += b.x; a.y += b.y; a.z += b.z; a.w += b.w;
        }
        float inv = 1.0f / fmaxf((float)(e0 - s0), 1.0f);
        ((float4*)sp)[t] = make_float4(a.x * inv, a.y * inv, a.z * inv, a.w * inv);
    }
    __syncthreads();

    if (t < MLP_HID_C) {
        float a = b1[t];
        #pragma unroll 8
        for (int k = 0; k < HID_C; ++k) a += sp[k] * W1[k * MLP_HID_C + t];
        shid[t] = fmaxf(a, 0.0f);
    }
    __syncthreads();

    if (t < N_CLS_C) {
        float a = b2[t];
        #pragma unroll
        for (int k = 0; k < MLP_HID_C; ++k) a += shid[k] * W2[k * N_CLS_C + t];
        sl[t] = a;
    }
    __syncthreads();

    if (t < N_CLS_C) {
        float m = sl[0];
        #pragma unroll
        for (int i = 1; i < N_CLS_C; ++i) m = fmaxf(m, sl[i]);
        float sum = 0.0f;
        #pragma unroll
        for (int i = 0; i < N_CLS_C; ++i) sum += expf(sl[i] - m);
        logits_out[(size_t)g * N_CLS_C + t] = sl[t] - m - logf(sum);
    }
}

extern "C" void kernel_launch(void* const* d_in, const int* in_sizes, int n_in,
                              void* d_out, int out_size, void* d_ws, size_t ws_size,
                              hipStream_t stream) {
    const float* x      = (const float*)d_in[0];
    const int*   ei     = (const int*)d_in[1];
    const int*   batch  = (const int*)d_in[2];
    const float* Wn     = (const float*)d_in[3];
    const float* Ws     = (const float*)d_in[4];
    const float* bias   = (const float*)d_in[5];
    const float* W1     = (const float*)d_in[6];
    const float* b1     = (const float*)d_in[7];
    const float* W2     = (const float*)d_in[8];
    const float* b2     = (const float*)d_in[9];

    float* out = (float*)d_out;
    int n_edges = in_sizes[1] / 2;
    const int* src = ei;
    const int* dst = ei + n_edges;

    // ws (ints): deg_i[N] | off[N+1] | cursor[N] | bsums[64] | start[G+1] |
    //            adj[E] | yn[N*64 u32]
    int* deg_i   = (int*)d_ws;
    int* off     = deg_i + N_NODES_C;
    int* cursor  = off + (N_NODES_C + 1);
    int* bsums   = cursor + N_NODES_C;
    int* start   = bsums + 64;
    int* adj     = start + (N_GRAPHS_C + 1);
    unsigned* yn = (unsigned*)(adj + n_edges);

    hipMemsetAsync(deg_i, 0, (size_t)N_NODES_C * sizeof(int), stream);

    hist_kernel<<<1024, 256, 0, stream>>>(dst, batch, deg_i, start, n_edges);
    scan1_kernel<<<N_SCAN_BLK, 256, 0, stream>>>(deg_i, bsums, N_NODES_C);
    scan3_kernel<<<N_SCAN_BLK, 256, 0, stream>>>(deg_i, bsums, off, cursor, N_NODES_C);
    scatter_kernel<<<2048, 256, 0, stream>>>(src, dst, cursor, adj, n_edges);

    gemm_kernel<<<782, 256, 0, stream>>>(x, Wn, Ws, bias, out, yn);

    gather_add_kernel<<<12500, 256, 0, stream>>>(yn, adj, off, out);

    poolhead_kernel<<<N_GRAPHS_C, 256, 0, stream>>>(out, start, W1, b1, W2, b2,
                                                    out + (size_t)N_NODES_C * HID_C);
}

// Round 8
// 117.480 us; speedup vs baseline: 1.4696x; 1.3344x over previous
//
#include <hip/hip_runtime.h>

#define N_NODES_C 50000
#define F_IN_C 64
#define HID_C 128
#define N_GRAPHS_C 500
#define N_CLS_C 10
#define MLP_HID_C 50
#define SCAN_TILE 1024
#define N_SCAN_BLK ((N_NODES_C + SCAN_TILE - 1) / SCAN_TILE)   // 49
#define N_TILES (N_NODES_C / 16)                               // 3125
#define N_RANGES 8
#define RANGE_SZ ((N_NODES_C + N_RANGES - 1) / N_RANGES)       // 6250

using short8 = __attribute__((ext_vector_type(8))) short;
using f32x4  = __attribute__((ext_vector_type(4))) float;

__device__ __forceinline__ int bl_i(int v, int l) {
    return __builtin_amdgcn_readlane(v, l);
}
__device__ __forceinline__ float uf(unsigned u) { return __uint_as_float(u); }

// round-to-nearest-even bf16 pack of two floats -> (lo=a, hi=b)
__device__ __forceinline__ unsigned pk_bf16(float a, float b) {
    unsigned ua = __float_as_uint(a), ub = __float_as_uint(b);
    ua += 0x7FFFu + ((ua >> 16) & 1u);
    ub += 0x7FFFu + ((ub >> 16) & 1u);
    return (ua >> 16) | (ub & 0xFFFF0000u);
}

union U8 { unsigned u[4]; uint4 q; short8 s; };

// ---------------------------------------------------------------------------
// Stage 1: degree histogram + per-edge rank (atomic-free scatter later) +
// bf16-compress x + graph bounds from sorted batch.
// ---------------------------------------------------------------------------
__global__ __launch_bounds__(256) void hist_kernel(
    const int* __restrict__ dst,
    const int* __restrict__ batch,
    const float* __restrict__ x,
    int* __restrict__ deg_i,
    int* __restrict__ rank,
    unsigned* __restrict__ xh,
    int* __restrict__ start,
    int n_edges)
{
    int tid = blockIdx.x * 256 + threadIdx.x;
    int stride = gridDim.x * 256;
    for (int e = tid; e < n_edges; e += stride)
        rank[e] = atomicAdd(&deg_i[dst[e]], 1);

    const float2* xf2 = (const float2*)x;
    int nx = N_NODES_C * (F_IN_C / 2);
    for (int i = tid; i < nx; i += stride) {
        float2 v = xf2[i];
        xh[i] = pk_bf16(v.x, v.y);
    }

    for (int i = tid; i < N_NODES_C; i += stride) {
        int b = batch[i];
        if (i == 0) { for (int g = 0; g <= b; ++g) start[g] = 0; }
        else { int p = batch[i - 1]; for (int g = p + 1; g <= b; ++g) start[g] = i; }
        if (i == N_NODES_C - 1) { for (int g = b + 1; g <= N_GRAPHS_C; ++g) start[g] = N_NODES_C; }
    }
}

// Stage 2a: per-1024-tile sums
__global__ __launch_bounds__(256) void scan1_kernel(
    const int* __restrict__ deg_i, int* __restrict__ bsums, int n)
{
    __shared__ int s[256];
    int base = blockIdx.x * SCAN_TILE;
    int t = threadIdx.x;
    int sum = 0;
    #pragma unroll
    for (int j = 0; j < 4; ++j) {
        int i = base + t * 4 + j;
        sum += (i < n) ? deg_i[i] : 0;
    }
    s[t] = sum;
    __syncthreads();
    for (int off = 128; off > 0; off >>= 1) {
        if (t < off) s[t] += s[t + off];
        __syncthreads();
    }
    if (t == 0) bsums[blockIdx.x] = s[0];
}

// Stage 2b: tile-prefix via wave-reduce of bsums + intra-tile exclusive scan
__global__ __launch_bounds__(256) void scan3_kernel(
    const int* __restrict__ deg_i, const int* __restrict__ bsums,
    int* __restrict__ off, int n)
{
    __shared__ int s[256];
    __shared__ int sbp;
    int b = blockIdx.x;
    int t = threadIdx.x;
    if (t < 64) {
        int v = (t < b) ? bsums[t] : 0;      // b <= 48 < 64
        #pragma unroll
        for (int m = 1; m < 64; m <<= 1) v += __shfl_xor(v, m, 64);
        if (t == 0) sbp = v;
    }
    int base = b * SCAN_TILE;
    int v4[4];
    int sum = 0;
    #pragma unroll
    for (int j = 0; j < 4; ++j) {
        int i = base + t * 4 + j;
        v4[j] = (i < n) ? deg_i[i] : 0;
        sum += v4[j];
    }
    s[t] = sum;
    __syncthreads();
    for (int o = 1; o < 256; o <<= 1) {
        int tmp = (t >= o) ? s[t - o] : 0;
        __syncthreads();
        s[t] += tmp;
        __syncthreads();
    }
    int run = s[t] - sum + sbp;
    #pragma unroll
    for (int j = 0; j < 4; ++j) {
        int i = base + t * 4 + j;
        if (i < n) off[i] = run;
        run += v4[j];
    }
    if (b == N_SCAN_BLK - 1 && t == 255) off[n] = sbp + s[255];
}

// ---------------------------------------------------------------------------
// Stage 3: atomic-free, XCD-range-partitioned scatter. Group g = blockIdx&7
// handles dst in [g*RANGE_SZ, ...): adj writes for a range come (heuristically)
// from one XCD -> no cross-XCD line ping-pong. rank makes it atomic-free.
// ---------------------------------------------------------------------------
__global__ __launch_bounds__(256) void scatter_kernel(
    const int* __restrict__ src, const int* __restrict__ dst,
    const int* __restrict__ rank, const int* __restrict__ off,
    int* __restrict__ adj, int n_edges)
{
    int g = blockIdx.x & 7;
    int lo = g * RANGE_SZ;
    for (int e = (blockIdx.x >> 3) * 256 + threadIdx.x; e < n_edges; e += 65536) {
        int d = dst[e];
        if ((unsigned)(d - lo) < (unsigned)RANGE_SZ)
            adj[off[d] + rank[e]] = src[e];
    }
}

// ---------------------------------------------------------------------------
// Gather-mean on bf16 x: agg[node] = mean of neighbors' xh rows (128B each).
// One wave per node, TWO edges per load instr: lanes 0-31 = even edge,
// lanes 32-63 = odd edge; lane's u32 = feature pair (2*(lane&31), +1).
// Fold halves with one shfl_xor(32). Source = 6.4MB, ~L2-resident.
// ---------------------------------------------------------------------------
__global__ __launch_bounds__(256) void gather_mean_kernel(
    const unsigned* __restrict__ xh,
    const int* __restrict__ adj,
    const int* __restrict__ off,
    unsigned* __restrict__ agg)
{
    int t = threadIdx.x;
    int wave = t >> 6, lane = t & 63;
    int node = blockIdx.x * 4 + wave;     // 12500 blocks * 4 = 50000 exact
    int o = off[node];
    int d = off[node + 1] - o;
    int half = lane >> 5;
    int col = lane & 31;
    float sx = 0.f, sy = 0.f;

    for (int j0 = 0; j0 < d; j0 += 64) {
        int c = d - j0; if (c > 64) c = 64;
        int nid = (lane < c) ? adj[o + j0 + lane] : 0;
        int j = 0;
        for (; j + 8 <= c; j += 8) {
            #pragma unroll
            for (int m = 0; m < 4; ++m) {
                int re = bl_i(nid, j + 2 * m);
                int ro = bl_i(nid, j + 2 * m + 1);
                int row = half ? ro : re;
                unsigned u = xh[(size_t)row * 32 + col];
                sx += uf(u << 16); sy += uf(u & 0xFFFF0000u);
            }
        }
        for (; j < c; j += 2) {
            int re = bl_i(nid, j);
            int ro = (j + 1 < c) ? bl_i(nid, j + 1) : re;
            int row = half ? ro : re;
            unsigned u = xh[(size_t)row * 32 + col];
            if (half && j + 1 >= c) u = 0u;
            sx += uf(u << 16); sy += uf(u & 0xFFFF0000u);
        }
    }
    sx += __shfl_xor(sx, 32, 64);
    sy += __shfl_xor(sy, 32, 64);
    if (half == 0) {
        float inv = 1.0f / fmaxf((float)d, 1.0f);
        agg[(size_t)node * 32 + col] = pk_bf16(sx * inv, sy * inv);
    }
}

// ---------------------------------------------------------------------------
// MFMA GEMM: emb = [x | agg] @ [[Ws],[Wn]] + b  (M=50000, K=128, N=128).
// W packed bf16-K-pairs in LDS ([64][129] u32, padded vs bank aliasing).
// One 16-row tile per wave; 782 blocks x 4 waves.
// A frag (16x16x32): A[lane&15][k=8*(lane>>4)+j]; B[k][lane&15]; D row=
// (lane>>4)*4+reg, col=lane&15.
// ---------------------------------------------------------------------------
__global__ __launch_bounds__(256) void gemm_kernel(
    const unsigned* __restrict__ xh,
    const unsigned* __restrict__ agg,
    const float* __restrict__ Wn,
    const float* __restrict__ Ws,
    const float* __restrict__ bias,
    float* __restrict__ emb_out)
{
    __shared__ unsigned sWk[64 * 129];   // sWk[kk][n] = pack(Wf[2kk][n], Wf[2kk+1][n])
    __shared__ float sb[128];
    int t = threadIdx.x;
    for (int e = t; e < 64 * 128; e += 256) {
        int kk = e >> 7, n = e & 127;
        float w0, w1;
        if (kk < 32) { w0 = Ws[(2 * kk) * 128 + n];      w1 = Ws[(2 * kk + 1) * 128 + n]; }
        else         { w0 = Wn[(2 * kk - 64) * 128 + n]; w1 = Wn[(2 * kk - 63) * 128 + n]; }
        sWk[kk * 129 + n] = pk_bf16(w0, w1);
    }
    if (t < 128) sb[t] = bias[t];
    __syncthreads();

    int wave = t >> 6, lane = t & 63;
    int lr = lane & 15, lg = lane >> 4;
    int tile = blockIdx.x * 4 + wave;
    if (tile >= N_TILES) return;

    // A frags: row = tile*16 + lr; s=0,1 from xh (k 0..63), s=2,3 from agg
    const uint4* xr = (const uint4*)(xh + ((size_t)tile * 16 + lr) * 32);
    const uint4* ar = (const uint4*)(agg + ((size_t)tile * 16 + lr) * 32);
    U8 A[4];
    A[0].q = xr[lg];
    A[1].q = xr[4 + lg];
    A[2].q = ar[lg];
    A[3].q = ar[4 + lg];

    #pragma unroll
    for (int c = 0; c < 8; ++c) {
        float bv = sb[c * 16 + lr];
        f32x4 acc = {bv, bv, bv, bv};
        #pragma unroll
        for (int s = 0; s < 4; ++s) {
            U8 B;
            #pragma unroll
            for (int jj = 0; jj < 4; ++jj)
                B.u[jj] = sWk[(16 * s + 4 * lg + jj) * 129 + c * 16 + lr];
            acc = __builtin_amdgcn_mfma_f32_16x16x32_bf16(A[s].s, B.s, acc, 0, 0, 0);
        }
        #pragma unroll
        for (int r = 0; r < 4; ++r)
            emb_out[((size_t)tile * 16 + lg * 4 + r) * 128 + c * 16 + lr] = acc[r];
    }
}

// ---------------------------------------------------------------------------
// Fused segment mean-pool of relu(emb) + MLP head + log_softmax.
// ---------------------------------------------------------------------------
__global__ __launch_bounds__(256) void poolhead_kernel(
    const float* __restrict__ emb, const int* __restrict__ start,
    const float* __restrict__ W1, const float* __restrict__ b1,
    const float* __restrict__ W2, const float* __restrict__ b2,
    float* __restrict__ logits_out)
{
    int g = blockIdx.x;
    int t = threadIdx.x;
    __shared__ float sp[HID_C];
    __shared__ float shid[MLP_HID_C];
    __shared__ float sl[N_CLS_C];
    __shared__ float4 red[256];

    int s0 = start[g], e0 = start[g + 1];
    int q = t & 31, r0 = t >> 5;
    const float4* e4 = (const float4*)emb;
    float4 acc = make_float4(0.f, 0.f, 0.f, 0.f);
    for (int r = s0 + r0; r < e0; r += 8) {
        float4 v = e4[(size_t)r * 32 + q];
        acc.x += fmaxf(v.x, 0.f); acc.y += fmaxf(v.y, 0.f);
        acc.z += fmaxf(v.z, 0.f); acc.w += fmaxf(v.w, 0.f);
    }
    red[t] = acc;
    __syncthreads();
    if (t < 32) {
        float4 a = red[t];
        #pragma unroll
        for (int r = 1; r < 8; ++r) {
            float4 b = red[t + 32 * r];
            a.x += b.x; a.y += b.y; a.z += b.z; a.w += b.w;
        }
        float inv = 1.0f / fmaxf((float)(e0 - s0), 1.0f);
        ((float4*)sp)[t] = make_float4(a.x * inv, a.y * inv, a.z * inv, a.w * inv);
    }
    __syncthreads();

    if (t < MLP_HID_C) {
        float a = b1[t];
        #pragma unroll 8
        for (int k = 0; k < HID_C; ++k) a += sp[k] * W1[k * MLP_HID_C + t];
        shid[t] = fmaxf(a, 0.0f);
    }
    __syncthreads();

    if (t < N_CLS_C) {
        float a = b2[t];
        #pragma unroll
        for (int k = 0; k < MLP_HID_C; ++k) a += shid[k] * W2[k * N_CLS_C + t];
        sl[t] = a;
    }
    __syncthreads();

    if (t < N_CLS_C) {
        float m = sl[0];
        #pragma unroll
        for (int i = 1; i < N_CLS_C; ++i) m = fmaxf(m, sl[i]);
        float sum = 0.0f;
        #pragma unroll
        for (int i = 0; i < N_CLS_C; ++i) sum += expf(sl[i] - m);
        logits_out[(size_t)g * N_CLS_C + t] = sl[t] - m - logf(sum);
    }
}

extern "C" void kernel_launch(void* const* d_in, const int* in_sizes, int n_in,
                              void* d_out, int out_size, void* d_ws, size_t ws_size,
                              hipStream_t stream) {
    const float* x      = (const float*)d_in[0];
    const int*   ei     = (const int*)d_in[1];
    const int*   batch  = (const int*)d_in[2];
    const float* Wn     = (const float*)d_in[3];
    const float* Ws     = (const float*)d_in[4];
    const float* bias   = (const float*)d_in[5];
    const float* W1     = (const float*)d_in[6];
    const float* b1     = (const float*)d_in[7];
    const float* W2     = (const float*)d_in[8];
    const float* b2     = (const float*)d_in[9];

    float* out = (float*)d_out;
    int n_edges = in_sizes[1] / 2;
    const int* src = ei;
    const int* dst = ei + n_edges;

    // ws (ints): deg_i[N] | off[N+1] | bsums[64] | start[G+1] | pad[2] |
    //            xh[N*32] | adj[E] | agg[N*32]   (rank aliases agg's head:
    //            rank dead after scatter, agg written after by gather)
    int* deg_i   = (int*)d_ws;
    int* off     = deg_i + N_NODES_C;
    int* bsums   = off + (N_NODES_C + 1);
    int* start   = bsums + 64;
    unsigned* xh = (unsigned*)(start + (N_GRAPHS_C + 1) + 2);   // 16B-aligned
    int* adj     = (int*)(xh + (size_t)N_NODES_C * 32);
    unsigned* agg = (unsigned*)(adj + n_edges);
    int* rank    = (int*)agg;

    hipMemsetAsync(deg_i, 0, (size_t)N_NODES_C * sizeof(int), stream);

    hist_kernel<<<1024, 256, 0, stream>>>(dst, batch, x, deg_i, rank, xh, start, n_edges);
    scan1_kernel<<<N_SCAN_BLK, 256, 0, stream>>>(deg_i, bsums, N_NODES_C);
    scan3_kernel<<<N_SCAN_BLK, 256, 0, stream>>>(deg_i, bsums, off, N_NODES_C);
    scatter_kernel<<<2048, 256, 0, stream>>>(src, dst, rank, off, adj, n_edges);

    gather_mean_kernel<<<12500, 256, 0, stream>>>(xh, adj, off, agg);

    gemm_kernel<<<782, 256, 0, stream>>>(xh, agg, Wn, Ws, bias, out);

    poolhead_kernel<<<N_GRAPHS_C, 256, 0, stream>>>(out, start, W1, b1, W2, b2,
                                                    out + (size_t)N_NODES_C * HID_C);
}